// Round 1
// baseline (239.555 us; speedup 1.0000x reference)
//
#include <hip/hip_runtime.h>
#include <hip/hip_bf16.h>

typedef unsigned int u32;
typedef unsigned short u16;
typedef __attribute__((ext_vector_type(8))) short short8;
typedef __attribute__((ext_vector_type(4))) float f32x4;

#define B_DIM 256
#define L_DIM 512
#define A_DIM 2048
#define W_DIM 64

__device__ __forceinline__ u32 fenc(float f){ u32 u=__float_as_uint(f); return (u>>31)? ~u : (u|0x80000000u); }
__device__ __forceinline__ float fdec(u32 k){ return (k>>31)? __uint_as_float(k&0x7FFFFFFFu) : __uint_as_float(~k); }
__device__ __forceinline__ u16 f2bf(float f){
  u32 u=__float_as_uint(f);
  u32 r=(u + 0x7FFFu + ((u>>16)&1u))>>16;
  return (u16)r;
}

// f32 -> bf16 convert, n % 4 == 0
__global__ __launch_bounds__(256) void cvt_kernel(const float* __restrict__ src, u16* __restrict__ dst, int n){
  int stride = gridDim.x*blockDim.x*4;
  for (int i = (blockIdx.x*blockDim.x + threadIdx.x)*4; i < n; i += stride){
    float4 v = *(const float4*)(src + i);
    ushort4 o;
    o.x = f2bf(v.x); o.y = f2bf(v.y); o.z = f2bf(v.z); o.w = f2bf(v.w);
    *(ushort4*)(dst + i) = o;
  }
}

// NT GEMM: C[m,n] = sum_k A[m,k]*B[n,k], A:[M][Kd] bf16, B:[N][Kd] bf16.
// MODE 0: store f32 + per-w (row/256) max via encoded atomicMax
// MODE 1: store bf16
// MODE 2: store f32
// MODE 3: store f32 (final output)
template<int MODE>
__global__ __launch_bounds__(256) void gemm_nt(
    const u16* __restrict__ Ab, const u16* __restrict__ Bb,
    float* __restrict__ Cf, u16* __restrict__ Cb, u32* __restrict__ menc,
    int M, int N, int Kd)
{
  __shared__ u16 As[128*32];
  __shared__ u16 Bs[128*32];
  __shared__ float wred[4];

  const int t = threadIdx.x;
  const int lane = t & 63;
  const int wave = t >> 6;
  const int wm = wave >> 1, wn = wave & 1;
  const int m0 = blockIdx.y * 128;
  const int n0 = blockIdx.x * 128;

  f32x4 acc[4][4];
  #pragma unroll
  for (int i=0;i<4;++i)
    #pragma unroll
    for (int j=0;j<4;++j) acc[i][j] = (f32x4)0.f;

  const int row_in = t >> 2;       // 0..63
  const int koff8 = (t & 3) * 8;   // bf16 element offset within BK=32
  const int wbase = (t & 192) * 8; // wave-uniform short offset

  const int nK = Kd >> 5;
  for (int kt = 0; kt < nK; ++kt){
    const int k0 = kt << 5;
    #pragma unroll
    for (int i = 0; i < 2; ++i){
      const u16* ga = Ab + (size_t)(m0 + i*64 + row_in)*Kd + k0 + koff8;
      const u16* gb = Bb + (size_t)(n0 + i*64 + row_in)*Kd + k0 + koff8;
      __builtin_amdgcn_global_load_lds((const __attribute__((address_space(1))) u32*)ga,
          (__attribute__((address_space(3))) u32*)(As + i*2048 + wbase), 16, 0, 0);
      __builtin_amdgcn_global_load_lds((const __attribute__((address_space(1))) u32*)gb,
          (__attribute__((address_space(3))) u32*)(Bs + i*2048 + wbase), 16, 0, 0);
    }
    __syncthreads();
    short8 af[4], bf[4];
    const int fr = lane & 15;
    const int fk = (lane >> 4) * 8;
    #pragma unroll
    for (int i=0;i<4;++i){
      af[i] = *(const short8*)(As + (wm*64 + i*16 + fr)*32 + fk);
      bf[i] = *(const short8*)(Bs + (wn*64 + i*16 + fr)*32 + fk);
    }
    #pragma unroll
    for (int i=0;i<4;++i)
      #pragma unroll
      for (int j=0;j<4;++j)
        acc[i][j] = __builtin_amdgcn_mfma_f32_16x16x32_bf16(af[i], bf[j], acc[i][j], 0, 0, 0);
    __syncthreads();
  }

  float vmax = -3.4e38f;
  #pragma unroll
  for (int i=0;i<4;++i){
    const int grow_base = m0 + wm*64 + i*16 + ((lane>>4)<<2);
    #pragma unroll
    for (int j=0;j<4;++j){
      const int gcol = n0 + wn*64 + j*16 + (lane & 15);
      #pragma unroll
      for (int r=0;r<4;++r){
        float v = acc[i][j][r];
        const size_t idx = (size_t)(grow_base + r)*N + gcol;
        if constexpr (MODE == 1) Cb[idx] = f2bf(v);
        else Cf[idx] = v;
        if constexpr (MODE == 0) vmax = fmaxf(vmax, v);
      }
    }
  }
  if constexpr (MODE == 0){
    #pragma unroll
    for (int off=32; off; off>>=1) vmax = fmaxf(vmax, __shfl_xor(vmax, off));
    if (lane == 0) wred[wave] = vmax;
    __syncthreads();
    if (t == 0){
      float m = fmaxf(fmaxf(wred[0], wred[1]), fmaxf(wred[2], wred[3]));
      atomicMax(menc + (m0 >> 8), fenc(m));
    }
  }
}

// context + gating: g[b,a] = sigmoid(Q) * (sum_w e*V) / (1e-8 + sum_w e)
__global__ __launch_bounds__(256) void reduce_kernel(
    const float* __restrict__ Kf, const u16* __restrict__ Vb,
    const float* __restrict__ Qf, const u32* __restrict__ menc,
    u16* __restrict__ g)
{
  __shared__ float ms[W_DIM];
  if (threadIdx.x < W_DIM) ms[threadIdx.x] = fdec(menc[threadIdx.x]);
  __syncthreads();
  const int total = B_DIM * A_DIM;
  for (int idx = blockIdx.x*blockDim.x + threadIdx.x; idx < total; idx += gridDim.x*blockDim.x){
    float num = 0.f, den = 1e-8f;
    #pragma unroll 4
    for (int w = 0; w < W_DIM; ++w){
      const size_t off = (size_t)w*total + idx;
      float kv = Kf[off];
      float e = expf(kv - ms[w]);
      float vv = __uint_as_float((u32)Vb[off] << 16);
      num += e*vv; den += e;
    }
    float q = Qf[idx];
    float sig = 1.f/(1.f + expf(-q));
    g[idx] = f2bf(sig * num / den);
  }
}

extern "C" void kernel_launch(void* const* d_in, const int* in_sizes, int n_in,
                              void* d_out, int out_size, void* d_ws, size_t ws_size,
                              hipStream_t stream){
  const float* zc = (const float*)d_in[0];
  const float* zw = (const float*)d_in[1];
  const float* Wq = (const float*)d_in[2];
  const float* Wk = (const float*)d_in[3];
  const float* Wv = (const float*)d_in[4];
  const float* Wo = (const float*)d_in[5];
  float* out = (float*)d_out;

  char* ws = (char*)d_ws;
  size_t off = 0;
  auto alloc = [&](size_t bytes)->void*{ void* p = ws + off; off += (bytes + 255) & ~(size_t)255; return p; };
  u16*  Zb   = (u16*) alloc((size_t)W_DIM*B_DIM*L_DIM*2);   // 16.8 MB
  u16*  zcb  = (u16*) alloc((size_t)B_DIM*L_DIM*2);
  u16*  Wqb  = (u16*) alloc((size_t)A_DIM*L_DIM*2);
  u16*  Wkb  = (u16*) alloc((size_t)A_DIM*L_DIM*2);
  u16*  Wvb  = (u16*) alloc((size_t)A_DIM*L_DIM*2);
  u16*  Wob  = (u16*) alloc((size_t)L_DIM*A_DIM*2);
  float* Kf  = (float*)alloc((size_t)W_DIM*B_DIM*A_DIM*4);  // 134 MB
  u16*  Vb   = (u16*) alloc((size_t)W_DIM*B_DIM*A_DIM*2);   // 67 MB
  float* Qf  = (float*)alloc((size_t)B_DIM*A_DIM*4);
  u16*  g    = (u16*) alloc((size_t)B_DIM*A_DIM*2);
  u32*  menc = (u32*) alloc(W_DIM*4);

  cvt_kernel<<<1024, 256, 0, stream>>>(zw,  Zb,  W_DIM*B_DIM*L_DIM);
  cvt_kernel<<<64,   256, 0, stream>>>(zc,  zcb, B_DIM*L_DIM);
  cvt_kernel<<<256,  256, 0, stream>>>(Wq,  Wqb, A_DIM*L_DIM);
  cvt_kernel<<<256,  256, 0, stream>>>(Wk,  Wkb, A_DIM*L_DIM);
  cvt_kernel<<<256,  256, 0, stream>>>(Wv,  Wvb, A_DIM*L_DIM);
  cvt_kernel<<<256,  256, 0, stream>>>(Wo,  Wob, L_DIM*A_DIM);
  hipMemsetAsync(menc, 0, W_DIM*4, stream);

  dim3 blk(256);
  // K = Zw @ Wk^T  (M=W*B, N=A, Kd=L) + per-w max
  gemm_nt<0><<<dim3(A_DIM/128, (W_DIM*B_DIM)/128), blk, 0, stream>>>(Zb, Wkb, Kf, nullptr, menc, W_DIM*B_DIM, A_DIM, L_DIM);
  // V = Zw @ Wv^T -> bf16
  gemm_nt<1><<<dim3(A_DIM/128, (W_DIM*B_DIM)/128), blk, 0, stream>>>(Zb, Wvb, nullptr, Vb, nullptr, W_DIM*B_DIM, A_DIM, L_DIM);
  // Q = zc @ Wq^T -> f32
  gemm_nt<2><<<dim3(A_DIM/128, B_DIM/128), blk, 0, stream>>>(zcb, Wqb, Qf, nullptr, nullptr, B_DIM, A_DIM, L_DIM);
  // g = sigmoid(Q) * context
  reduce_kernel<<<1024, 256, 0, stream>>>(Kf, Vb, Qf, menc, g);
  // out = g @ Wo^T  (M=B, N=L, Kd=A)
  gemm_nt<3><<<dim3(L_DIM/128, B_DIM/128), blk, 0, stream>>>(g, Wob, out, nullptr, nullptr, B_DIM, L_DIM, A_DIM);
}